// Round 1
// baseline (479.505 us; speedup 1.0000x reference)
//
#include <hip/hip_runtime.h>

#define VOCAB 16384
#define N_Q   16384   // B*h*w = 16*32*32
#define C     32
#define HW    1024    // h*w
#define VCHUNKS 16
#define CODES_PER_CHUNK (VOCAB / VCHUNKS)  // 1024
#define TILE  128

// ---------------- kernel 1: ||e_j||^2 ----------------
__global__ __launch_bounds__(256) void k_enorm(const float* __restrict__ emb,
                                               float* __restrict__ enorm) {
    int j = blockIdx.x * 256 + threadIdx.x;
    if (j >= VOCAB) return;
    const float4* e4 = reinterpret_cast<const float4*>(emb + j * C);
    float s = 0.f;
#pragma unroll
    for (int k = 0; k < 8; ++k) {
        float4 v = e4[k];
        s += v.x * v.x + v.y * v.y + v.z * v.z + v.w * v.w;
    }
    enorm[j] = s;
}

// ---------------- kernel 2: repack conv weights to [tap][cin][cout] ----------------
__global__ __launch_bounds__(256) void k_wpack(const float* __restrict__ w,
                                               float* __restrict__ wp) {
    int i = blockIdx.x * 256 + threadIdx.x;  // over 32*32*9 = 9216
    if (i >= C * C * 9) return;
    int cout = i / (C * 9);
    int r = i % (C * 9);
    int cin = r / 9;
    int tap = r % 9;
    wp[(tap * C + cin) * C + cout] = w[i];
}

// ---------------- kernel 3: partial argmin over vocab chunks ----------------
// dist = ||e||^2 - 2 q.e   (q-norm constant per query, irrelevant for argmin)
__global__ __launch_bounds__(256) void k_argmin(const float* __restrict__ f,
                                                const float* __restrict__ emb,
                                                const float* __restrict__ enorm,
                                                float* __restrict__ pdist,
                                                int* __restrict__ pidx) {
    __shared__ float sE[TILE * C];
    __shared__ float sN[TILE];
    int n = blockIdx.x * 256 + threadIdx.x;  // query id; b fixed within block
    int b = n >> 10;
    int rem = n & 1023;  // y*32+x
    float q[C];
#pragma unroll
    for (int c = 0; c < C; ++c) q[c] = f[(b * C + c) * HW + rem];

    int base = blockIdx.y * CODES_PER_CHUNK;
    float best = 3.4e38f;
    int bidx = 0;
    for (int t = 0; t < CODES_PER_CHUNK / TILE; ++t) {
        __syncthreads();
        const float4* src = reinterpret_cast<const float4*>(emb + (base + t * TILE) * C);
        float4* dst = reinterpret_cast<float4*>(sE);
#pragma unroll
        for (int i = 0; i < 4; ++i) dst[threadIdx.x + 256 * i] = src[threadIdx.x + 256 * i];
        if (threadIdx.x < TILE) sN[threadIdx.x] = enorm[base + t * TILE + threadIdx.x];
        __syncthreads();
        for (int j = 0; j < TILE; ++j) {
            const float4* e4 = reinterpret_cast<const float4*>(sE + j * C);
            float dot = 0.f;
#pragma unroll
            for (int k = 0; k < 8; ++k) {
                float4 v = e4[k];
                dot += q[4 * k] * v.x + q[4 * k + 1] * v.y + q[4 * k + 2] * v.z + q[4 * k + 3] * v.w;
            }
            float d = fmaf(-2.f, dot, sN[j]);
            if (d < best) { best = d; bidx = base + t * TILE + j; }  // strict < => first min
        }
    }
    pdist[blockIdx.y * N_Q + n] = best;
    pidx[blockIdx.y * N_Q + n] = bidx;
}

// ---------------- kernel 4: final argmin, bincount, gather zq (NHWC) ----------------
__global__ __launch_bounds__(256) void k_reduce(const float* __restrict__ pdist,
                                                const int* __restrict__ pidx,
                                                const float* __restrict__ emb,
                                                int* __restrict__ counts,
                                                float* __restrict__ zq) {
    int n = blockIdx.x * 256 + threadIdx.x;
    float best = 3.4e38f;
    int bi = 0;
    for (int c = 0; c < VCHUNKS; ++c) {  // ascending chunk => first-min tie-break
        float d = pdist[c * N_Q + n];
        int ix = pidx[c * N_Q + n];
        if (d < best) { best = d; bi = ix; }
    }
    atomicAdd(&counts[bi], 1);
    const float4* e4 = reinterpret_cast<const float4*>(emb + bi * C);
    float4* z4 = reinterpret_cast<float4*>(zq + n * C);
#pragma unroll
    for (int k = 0; k < 8; ++k) z4[k] = e4[k];
}

// ---------------- kernel 5: conv3x3 residual + fhat + loss partials ----------------
// zq is NHWC [b][y][x][c]; out is NCHW. block = (b, 8-row tile), 256 thr = 8x32 pixels
__global__ __launch_bounds__(256) void k_conv(const float* __restrict__ zq,
                                              const float* __restrict__ wp,
                                              const float* __restrict__ bias,
                                              const float* __restrict__ f,
                                              float* __restrict__ out,
                                              float* __restrict__ lpart) {
    __shared__ float sZ[320 * 33];  // 10 rows x 32 cols, 33-float pixel stride (bank pad)
    __shared__ float red[256];
    int blk = blockIdx.x;
    int b = blk >> 2;
    int r0 = (blk & 3) * 8;
    int tid = threadIdx.x;

    for (int i = tid; i < 320; i += 256) {
        int row = i >> 5, col = i & 31;
        int gy = r0 - 1 + row;
        float4* d = reinterpret_cast<float4*>(&sZ[i * 33]);
        if (gy >= 0 && gy < 32) {
            const float4* s = reinterpret_cast<const float4*>(zq + ((b * HW) + gy * 32 + col) * C);
#pragma unroll
            for (int k = 0; k < 8; ++k) d[k] = s[k];
        } else {
#pragma unroll
            for (int k = 0; k < 8; ++k) d[k] = make_float4(0.f, 0.f, 0.f, 0.f);
        }
    }
    __syncthreads();

    int ty = tid >> 5, tx = tid & 31;
    int gy = r0 + ty;
    float lsum = 0.f;
    for (int co = 0; co < C; co += 8) {
        float acc[8];
#pragma unroll
        for (int u = 0; u < 8; ++u) acc[u] = bias[co + u];
        for (int dy = -1; dy <= 1; ++dy) {
            for (int dx = -1; dx <= 1; ++dx) {
                int gx = tx + dx;
                if (gx < 0 || gx >= 32) continue;  // horizontal zero-pad
                const float* zp = &sZ[((ty + 1 + dy) * 32 + gx) * 33];
                int tap = (dy + 1) * 3 + (dx + 1);
                const float* wtap = &wp[tap * C * C + co];
#pragma unroll
                for (int cin = 0; cin < C; ++cin) {
                    float z = zp[cin];
                    const float* wrow = wtap + cin * C;
#pragma unroll
                    for (int u = 0; u < 8; ++u) acc[u] = fmaf(z, wrow[u], acc[u]);
                }
            }
        }
#pragma unroll
        for (int u = 0; u < 8; ++u) {
            int cc = co + u;
            float zqv = sZ[((ty + 1) * 32 + tx) * 33 + cc];
            float fh = 0.5f * (zqv + acc[u]);  // h*(1-r) + (conv+b)*r, r=0.5
            int off = (b * C + cc) * HW + gy * 32 + tx;
            out[off] = fh;
            float diff = fh - f[off];
            lsum += diff * diff;
        }
    }
    red[tid] = lsum;
    __syncthreads();
    for (int s = 128; s > 0; s >>= 1) {
        if (tid < s) red[tid] += red[tid + s];
        __syncthreads();
    }
    if (tid == 0) lpart[blockIdx.x] = red[0];
}

// ---------------- kernel 6: scalars ----------------
__global__ __launch_bounds__(256) void k_final(const float* __restrict__ lpart,
                                               const int* __restrict__ counts,
                                               float* __restrict__ out) {
    __shared__ float red[256];
    __shared__ int redi[256];
    int tid = threadIdx.x;
    int used = 0;
    for (int i = tid; i < VOCAB; i += 256) used += (counts[i] != 0) ? 1 : 0;
    red[tid] = (tid < 64) ? lpart[tid] : 0.f;
    redi[tid] = used;
    __syncthreads();
    for (int s = 128; s > 0; s >>= 1) {
        if (tid < s) { red[tid] += red[tid + s]; redi[tid] += redi[tid + s]; }
        __syncthreads();
    }
    if (tid == 0) {
        out[N_Q * C]     = 1.25f * red[0] / (float)(N_Q * C);      // (1+BETA)*MSE
        out[N_Q * C + 1] = 100.f * (float)redi[0] / (float)VOCAB;  // counts>=1 <=> prob>0.01/V
    }
}

extern "C" void kernel_launch(void* const* d_in, const int* in_sizes, int n_in,
                              void* d_out, int out_size, void* d_ws, size_t ws_size,
                              hipStream_t stream) {
    const float* f     = (const float*)d_in[0];
    const float* emb   = (const float*)d_in[1];
    const float* convw = (const float*)d_in[2];
    const float* convb = (const float*)d_in[3];
    float* out = (float*)d_out;
    float* ws  = (float*)d_ws;

    float* enorm  = ws;                         // 16384
    float* pdist  = ws + 16384;                 // 262144
    int*   pidx   = (int*)(ws + 278528);        // 262144
    int*   counts = (int*)(ws + 540672);        // 16384
    float* zq     = ws + 557056;                // 524288 (NHWC)
    float* wp     = ws + 1081344;               // 9216
    float* lpart  = ws + 1090560;               // 64
    // total ~4.36 MB of ws

    hipMemsetAsync(counts, 0, VOCAB * sizeof(int), stream);
    k_enorm<<<VOCAB / 256, 256, 0, stream>>>(emb, enorm);
    k_wpack<<<(C * C * 9 + 255) / 256, 256, 0, stream>>>(convw, wp);
    dim3 g2(N_Q / 256, VCHUNKS);
    k_argmin<<<g2, 256, 0, stream>>>(f, emb, enorm, pdist, pidx);
    k_reduce<<<N_Q / 256, 256, 0, stream>>>(pdist, pidx, emb, counts, zq);
    k_conv<<<64, 256, 0, stream>>>(zq, wp, convb, f, out, lpart);
    k_final<<<1, 256, 0, stream>>>(lpart, counts, out);
}

// Round 6
// 167.283 us; speedup vs baseline: 2.8664x; 2.8664x over previous
//
#include <hip/hip_runtime.h>

#define VOCAB 16384
#define N_Q   16384   // B*h*w = 16*32*32
#define C     32
#define HW    1024    // h*w
#define VCH   16
#define CODES_PER_CH (VOCAB / VCH)  // 1024

typedef short short8 __attribute__((ext_vector_type(8)));
typedef float f32x4  __attribute__((ext_vector_type(4)));

__device__ inline ushort f2bf_rne(float x) {
    unsigned u = __float_as_uint(x);
    unsigned r = u + 0x7FFFu + ((u >> 16) & 1u);
    return (ushort)(r >> 16);
}
__device__ inline float bf2f(ushort h) { return __uint_as_float(((unsigned)h) << 16); }

// ---------------- ||e_j||^2 (fp32 exact) ----------------
__global__ __launch_bounds__(256) void k_enorm(const float* __restrict__ emb,
                                               float* __restrict__ enorm) {
    int j = blockIdx.x * 256 + threadIdx.x;
    if (j >= VOCAB) return;
    const float4* e4 = reinterpret_cast<const float4*>(emb + j * C);
    float s = 0.f;
#pragma unroll
    for (int k = 0; k < 8; ++k) {
        float4 v = e4[k];
        s += v.x * v.x + v.y * v.y + v.z * v.z + v.w * v.w;
    }
    enorm[j] = s;
}

// ---------------- pack E -> bf16 hi/lo MFMA B-fragments ----------------
// frag layout: sub-strip t=j>>4, lane=((k>>3)<<4)|(j&15), elem=k&7
// plane offset = t*512 + lane*8 + elem  (ushort units)
__global__ __launch_bounds__(256) void k_packE(const float* __restrict__ emb,
                                               ushort* __restrict__ hi, ushort* __restrict__ lo) {
    int i = blockIdx.x * 256 + threadIdx.x;   // 65536 threads: (j, k-octet)
    int j = i & (VOCAB - 1);
    int ko = i >> 14;  // 0..3
    short8 sh, sl;
#pragma unroll
    for (int e = 0; e < 8; ++e) {
        float v = emb[j * C + ko * 8 + e];
        ushort h = f2bf_rne(v);
        sh[e] = (short)h;
        sl[e] = (short)f2bf_rne(v - bf2f(h));
    }
    int off = (j >> 4) * 512 + (((ko << 4) | (j & 15)) * 8);
    *reinterpret_cast<short8*>(hi + off) = sh;
    *reinterpret_cast<short8*>(lo + off) = sl;
}

// ---------------- pack Q (f is NCHW) -> bf16 hi/lo MFMA A-fragments ----------------
__global__ __launch_bounds__(256) void k_packQ(const float* __restrict__ f,
                                               ushort* __restrict__ hi, ushort* __restrict__ lo) {
    int i = blockIdx.x * 256 + threadIdx.x;   // 65536 threads: (n, c-octet)
    int n = i & (N_Q - 1);
    int co = i >> 14;  // 0..3
    int b = n >> 10, rem = n & 1023;
    short8 sh, sl;
#pragma unroll
    for (int e = 0; e < 8; ++e) {
        int c = co * 8 + e;
        float v = f[(b * C + c) * HW + rem];
        ushort h = f2bf_rne(v);
        sh[e] = (short)h;
        sl[e] = (short)f2bf_rne(v - bf2f(h));
    }
    int off = (n >> 4) * 512 + (((co << 4) | (n & 15)) * 8);
    *reinterpret_cast<short8*>(hi + off) = sh;
    *reinterpret_cast<short8*>(lo + off) = sl;
}

// ---------------- repack conv weights to [tap][cin][cout] ----------------
__global__ __launch_bounds__(256) void k_wpack(const float* __restrict__ w,
                                               float* __restrict__ wp) {
    int i = blockIdx.x * 256 + threadIdx.x;
    if (i >= C * C * 9) return;
    int cout = i / (C * 9);
    int r = i % (C * 9);
    int cin = r / 9;
    int tap = r % 9;
    wp[(tap * C + cin) * C + cout] = w[i];
}

// ---------------- MFMA argmin: dist = ||e||^2 - 2 q.e via split-bf16 ----------------
// wave handles 64 queries (4 sub-strips of 16); loops a 1024-code chunk in 16-code tiles
__global__ __launch_bounds__(256) void k_argmin_mfma(
    const ushort* __restrict__ Qhi, const ushort* __restrict__ Qlo,
    const ushort* __restrict__ Ehi, const ushort* __restrict__ Elo,
    const float* __restrict__ enorm,
    float* __restrict__ pdist, int* __restrict__ pidx) {
    int tid = threadIdx.x;
    int lane = tid & 63;
    int w = tid >> 6;                    // wave in block: 0..3
    int strip = blockIdx.x * 4 + w;      // 0..255 -> queries strip*64..+64
    int chunk = blockIdx.y;              // 0..15

    short8 a_hi[4], a_lo[4];
#pragma unroll
    for (int qq = 0; qq < 4; ++qq) {
        int ss = strip * 4 + qq;
        a_hi[qq] = *reinterpret_cast<const short8*>(Qhi + ss * 512 + lane * 8);
        a_lo[qq] = *reinterpret_cast<const short8*>(Qlo + ss * 512 + lane * 8);
    }
    float best[4][4];
    int bidx[4][4];
#pragma unroll
    for (int qq = 0; qq < 4; ++qq)
#pragma unroll
        for (int r = 0; r < 4; ++r) { best[qq][r] = 3.4e38f; bidx[qq][r] = 0; }

    int t0 = chunk * (CODES_PER_CH / 16);
    int curcode = chunk * CODES_PER_CH + (lane & 15);
    const ushort* pe_hi = Ehi + t0 * 512 + lane * 8;
    const ushort* pe_lo = Elo + t0 * 512 + lane * 8;
    const float* pen = enorm + chunk * CODES_PER_CH + (lane & 15);

#pragma unroll 2
    for (int t = 0; t < CODES_PER_CH / 16; ++t) {
        short8 b_hi = *reinterpret_cast<const short8*>(pe_hi); pe_hi += 512;
        short8 b_lo = *reinterpret_cast<const short8*>(pe_lo); pe_lo += 512;
        float en = *pen; pen += 16;
#pragma unroll
        for (int qq = 0; qq < 4; ++qq) {
            f32x4 acc = {0.f, 0.f, 0.f, 0.f};
            acc = __builtin_amdgcn_mfma_f32_16x16x32_bf16(a_hi[qq], b_hi, acc, 0, 0, 0);
            acc = __builtin_amdgcn_mfma_f32_16x16x32_bf16(a_hi[qq], b_lo, acc, 0, 0, 0);
            acc = __builtin_amdgcn_mfma_f32_16x16x32_bf16(a_lo[qq], b_hi, acc, 0, 0, 0);
            acc = __builtin_amdgcn_mfma_f32_16x16x32_bf16(a_lo[qq], b_lo, acc, 0, 0, 0);
#pragma unroll
            for (int r = 0; r < 4; ++r) {
                float d = fmaf(acc[r], -2.f, en);
                if (d < best[qq][r]) { best[qq][r] = d; bidx[qq][r] = curcode; }
            }
        }
        curcode += 16;
    }

    // reduce across the 16 lanes holding each query row (cols live at lane&15)
#pragma unroll
    for (int qq = 0; qq < 4; ++qq)
#pragma unroll
        for (int r = 0; r < 4; ++r) {
            float d = best[qq][r];
            int ix = bidx[qq][r];
#pragma unroll
            for (int m = 1; m < 16; m <<= 1) {
                float od = __shfl_xor(d, m, 64);
                int oi = __shfl_xor(ix, m, 64);
                if (od < d || (od == d && oi < ix)) { d = od; ix = oi; }
            }
            if ((lane & 15) == 0) {
                int row = ((lane >> 4) * 4) + r;
                int n = (strip * 4 + qq) * 16 + row;
                pdist[chunk * N_Q + n] = d;
                pidx[chunk * N_Q + n] = ix;
            }
        }
}

// ---------------- final argmin, bincount, gather zq (NHWC) ----------------
__global__ __launch_bounds__(256) void k_reduce(const float* __restrict__ pdist,
                                                const int* __restrict__ pidx,
                                                const float* __restrict__ emb,
                                                int* __restrict__ counts,
                                                float* __restrict__ zq) {
    int n = blockIdx.x * 256 + threadIdx.x;
    float best = 3.4e38f;
    int bi = 0;
    for (int c = 0; c < VCH; ++c) {  // ascending chunk => first-min tie-break
        float d = pdist[c * N_Q + n];
        int ix = pidx[c * N_Q + n];
        if (d < best || (d == best && ix < bi)) { best = d; bi = ix; }
    }
    atomicAdd(&counts[bi], 1);
    const float4* e4 = reinterpret_cast<const float4*>(emb + bi * C);
    float4* z4 = reinterpret_cast<float4*>(zq + n * C);
#pragma unroll
    for (int k = 0; k < 8; ++k) z4[k] = e4[k];
}

// ---------------- conv3x3 residual + fhat + loss partials ----------------
__global__ __launch_bounds__(256) void k_conv(const float* __restrict__ zq,
                                              const float* __restrict__ wp,
                                              const float* __restrict__ bias,
                                              const float* __restrict__ f,
                                              float* __restrict__ out,
                                              float* __restrict__ lpart) {
    __shared__ float sZ[320 * 33];
    __shared__ float red[256];
    int blk = blockIdx.x;
    int b = blk >> 2;
    int r0 = (blk & 3) * 8;
    int tid = threadIdx.x;

    for (int i = tid; i < 320; i += 256) {
        int row = i >> 5, col = i & 31;
        int gy = r0 - 1 + row;
        float4* d = reinterpret_cast<float4*>(&sZ[i * 33]);
        if (gy >= 0 && gy < 32) {
            const float4* s = reinterpret_cast<const float4*>(zq + ((b * HW) + gy * 32 + col) * C);
#pragma unroll
            for (int k = 0; k < 8; ++k) d[k] = s[k];
        } else {
#pragma unroll
            for (int k = 0; k < 8; ++k) d[k] = make_float4(0.f, 0.f, 0.f, 0.f);
        }
    }
    __syncthreads();

    int ty = tid >> 5, tx = tid & 31;
    int gy = r0 + ty;
    float lsum = 0.f;
    for (int co = 0; co < C; co += 8) {
        float acc[8];
#pragma unroll
        for (int u = 0; u < 8; ++u) acc[u] = bias[co + u];
        for (int dy = -1; dy <= 1; ++dy) {
            for (int dx = -1; dx <= 1; ++dx) {
                int gx = tx + dx;
                if (gx < 0 || gx >= 32) continue;
                const float* zp = &sZ[((ty + 1 + dy) * 32 + gx) * 33];
                int tap = (dy + 1) * 3 + (dx + 1);
                const float* wtap = &wp[tap * C * C + co];
#pragma unroll
                for (int cin = 0; cin < C; ++cin) {
                    float z = zp[cin];
                    const float* wrow = wtap + cin * C;
#pragma unroll
                    for (int u = 0; u < 8; ++u) acc[u] = fmaf(z, wrow[u], acc[u]);
                }
            }
        }
#pragma unroll
        for (int u = 0; u < 8; ++u) {
            int cc = co + u;
            float zqv = sZ[((ty + 1) * 32 + tx) * 33 + cc];
            float fh = 0.5f * (zqv + acc[u]);
            int off = (b * C + cc) * HW + gy * 32 + tx;
            out[off] = fh;
            float diff = fh - f[off];
            lsum += diff * diff;
        }
    }
    red[tid] = lsum;
    __syncthreads();
    for (int s = 128; s > 0; s >>= 1) {
        if (tid < s) red[tid] += red[tid + s];
        __syncthreads();
    }
    if (tid == 0) lpart[blockIdx.x] = red[0];
}

// ---------------- scalars ----------------
__global__ __launch_bounds__(256) void k_final(const float* __restrict__ lpart,
                                               const int* __restrict__ counts,
                                               float* __restrict__ out) {
    __shared__ float red[256];
    __shared__ int redi[256];
    int tid = threadIdx.x;
    int used = 0;
    for (int i = tid; i < VOCAB; i += 256) used += (counts[i] != 0) ? 1 : 0;
    red[tid] = (tid < 64) ? lpart[tid] : 0.f;
    redi[tid] = used;
    __syncthreads();
    for (int s = 128; s > 0; s >>= 1) {
        if (tid < s) { red[tid] += red[tid + s]; redi[tid] += redi[tid + s]; }
        __syncthreads();
    }
    if (tid == 0) {
        out[N_Q * C]     = 1.25f * red[0] / (float)(N_Q * C);
        out[N_Q * C + 1] = 100.f * (float)redi[0] / (float)VOCAB;
    }
}

extern "C" void kernel_launch(void* const* d_in, const int* in_sizes, int n_in,
                              void* d_out, int out_size, void* d_ws, size_t ws_size,
                              hipStream_t stream) {
    const float* f     = (const float*)d_in[0];
    const float* emb   = (const float*)d_in[1];
    const float* convw = (const float*)d_in[2];
    const float* convb = (const float*)d_in[3];
    float* out = (float*)d_out;
    float* ws  = (float*)d_ws;

    // float-unit offsets into ws
    float*  enorm  = ws;                          // 16384
    float*  pdist  = ws + 16384;                  // 262144
    int*    pidx   = (int*)(ws + 278528);         // 262144
    int*    counts = (int*)(ws + 540672);         // 16384
    float*  wp     = ws + 557056;                 // 9216
    float*  lpart  = ws + 566272;                 // 64
    ushort* Qhi    = (ushort*)(ws + 566336);      // 524288 ushorts (262144 float slots)
    ushort* Qlo    = (ushort*)(ws + 828480);      // 524288 ushorts
    ushort* Ehi    = (ushort*)(ws + 1090624);     // 524288 ushorts
    ushort* Elo    = (ushort*)(ws + 1352768);     // 524288 ushorts
    float*  zq     = ws + 566336;                 // aliases Qhi/Qlo (dead after argmin)
    // total = 1,614,912 floats ~= 6.46 MB

    hipMemsetAsync(counts, 0, VOCAB * sizeof(int), stream);
    k_enorm<<<VOCAB / 256, 256, 0, stream>>>(emb, enorm);
    k_wpack<<<(C * C * 9 + 255) / 256, 256, 0, stream>>>(convw, wp);
    k_packE<<<256, 256, 0, stream>>>(emb, Ehi, Elo);
    k_packQ<<<256, 256, 0, stream>>>(f, Qhi, Qlo);
    dim3 g2(64, VCH);
    k_argmin_mfma<<<g2, 256, 0, stream>>>(Qhi, Qlo, Ehi, Elo, enorm, pdist, pidx);
    k_reduce<<<N_Q / 256, 256, 0, stream>>>(pdist, pidx, emb, counts, zq);
    k_conv<<<64, 256, 0, stream>>>(zq, wp, convb, f, out, lpart);
    k_final<<<1, 256, 0, stream>>>(lpart, counts, out);
}

// Round 7
// 153.600 us; speedup vs baseline: 3.1218x; 1.0891x over previous
//
#include <hip/hip_runtime.h>

#define VOCAB 16384
#define N_Q   16384   // B*h*w = 16*32*32
#define C     32
#define HW    1024    // h*w
#define VCH   16
#define CODES_PER_CH (VOCAB / VCH)  // 1024
#define TILES_PER_CH (CODES_PER_CH / 16)  // 64

typedef short short8 __attribute__((ext_vector_type(8)));
typedef float f32x4  __attribute__((ext_vector_type(4)));

__device__ inline ushort f2bf_rne(float x) {
    unsigned u = __float_as_uint(x);
    unsigned r = u + 0x7FFFu + ((u >> 16) & 1u);
    return (ushort)(r >> 16);
}
__device__ inline float bf2f(ushort h) { return __uint_as_float(((unsigned)h) << 16); }

// ---------------- fused: enorm2 (=||e||^2 / 2) + pack E -> bf16 hi/lo B-frags ----------------
// frag layout (verified on HW, round 6): tile tg=j>>4, lane=(ko<<4)|(j&15), elem 0..7
// plane ushort offset = tg*512 + lane*8 + elem
__global__ __launch_bounds__(256) void k_prepE(const float* __restrict__ emb,
                                               float* __restrict__ enorm2,
                                               ushort* __restrict__ hi, ushort* __restrict__ lo) {
    int j = blockIdx.x * 256 + threadIdx.x;   // code row
    if (j >= VOCAB) return;
    const float4* e4 = reinterpret_cast<const float4*>(emb + j * C);
    float s = 0.f;
    float v[C];
#pragma unroll
    for (int k = 0; k < 8; ++k) {
        float4 t = e4[k];
        v[4 * k] = t.x; v[4 * k + 1] = t.y; v[4 * k + 2] = t.z; v[4 * k + 3] = t.w;
        s += t.x * t.x + t.y * t.y + t.z * t.z + t.w * t.w;
    }
    enorm2[j] = 0.5f * s;
#pragma unroll
    for (int ko = 0; ko < 4; ++ko) {
        short8 sh, sl;
#pragma unroll
        for (int e = 0; e < 8; ++e) {
            float x = v[ko * 8 + e];
            ushort h = f2bf_rne(x);
            sh[e] = (short)h;
            sl[e] = (short)f2bf_rne(x - bf2f(h));
        }
        int off = (j >> 4) * 512 + (((ko << 4) | (j & 15)) * 8);
        *reinterpret_cast<short8*>(hi + off) = sh;
        *reinterpret_cast<short8*>(lo + off) = sl;
    }
}

// ---------------- pack Q (NCHW f) -> NEGATED bf16 hi/lo A-frags ----------------
__global__ __launch_bounds__(256) void k_packQ(const float* __restrict__ f,
                                               ushort* __restrict__ hi, ushort* __restrict__ lo) {
    int i = blockIdx.x * 256 + threadIdx.x;   // 65536: (n fast, c-octet slow) -> coalesced
    int n = i & (N_Q - 1);
    int co = i >> 14;  // 0..3
    int b = n >> 10, rem = n & 1023;
    short8 sh, sl;
#pragma unroll
    for (int e = 0; e < 8; ++e) {
        int c = co * 8 + e;
        float x = -f[(b * C + c) * HW + rem];   // negated!
        ushort h = f2bf_rne(x);
        sh[e] = (short)h;
        sl[e] = (short)f2bf_rne(x - bf2f(h));
    }
    int off = (n >> 4) * 512 + (((co << 4) | (n & 15)) * 8);
    *reinterpret_cast<short8*>(hi + off) = sh;
    *reinterpret_cast<short8*>(lo + off) = sl;
}

// ---------------- repack conv weights to [tap][cin][cout] ----------------
__global__ __launch_bounds__(256) void k_wpack(const float* __restrict__ w,
                                               float* __restrict__ wp) {
    int i = blockIdx.x * 256 + threadIdx.x;
    if (i >= C * C * 9) return;
    int cout = i / (C * 9);
    int r = i % (C * 9);
    int cin = r / 9;
    int tap = r % 9;
    wp[(tap * C + cin) * C + cout] = w[i];
}

// ---------------- MFMA argmin: acc = en/2 - q.e (4-way split-bf16), atomicMin key ----------------
// wave = 32 queries (2 sub-strips of 16), chunk = 1024 codes in 64 tiles of 16
__global__ __launch_bounds__(256, 8) void k_argmin(
    const ushort* __restrict__ Qhi, const ushort* __restrict__ Qlo,
    const ushort* __restrict__ Ehi, const ushort* __restrict__ Elo,
    const float* __restrict__ enorm2,
    unsigned long long* __restrict__ keys) {
    int tid = threadIdx.x;
    int lane = tid & 63;
    int w = tid >> 6;
    int strip = blockIdx.x * 4 + w;      // 0..511 -> queries strip*32..+32
    int chunk = blockIdx.y;              // 0..15

    short8 a_hi[2], a_lo[2];
#pragma unroll
    for (int qq = 0; qq < 2; ++qq) {
        int ss = strip * 2 + qq;
        a_hi[qq] = *reinterpret_cast<const short8*>(Qhi + ss * 512 + lane * 8);
        a_lo[qq] = *reinterpret_cast<const short8*>(Qlo + ss * 512 + lane * 8);
    }
    float best[2][4];
    int   bt[2][4];
#pragma unroll
    for (int qq = 0; qq < 2; ++qq)
#pragma unroll
        for (int r = 0; r < 4; ++r) { best[qq][r] = 3.4e38f; bt[qq][r] = 0; }

    // per-lane bases: tile tg = chunk*64 + t; frag at tg*64 short8 + lane
    const short8* pe_hi = reinterpret_cast<const short8*>(Ehi) + (size_t)chunk * TILES_PER_CH * 64 + lane;
    const short8* pe_lo = reinterpret_cast<const short8*>(Elo) + (size_t)chunk * TILES_PER_CH * 64 + lane;
    const float*  pen   = enorm2 + chunk * CODES_PER_CH + (lane & 15);

#pragma unroll 4
    for (int t = 0; t < TILES_PER_CH; ++t) {
        short8 b_hi = pe_hi[t * 64];
        short8 b_lo = pe_lo[t * 64];
        float  en2  = pen[t * 16];
        f32x4 acc0 = {en2, en2, en2, en2};
        f32x4 acc1 = {en2, en2, en2, en2};
        acc0 = __builtin_amdgcn_mfma_f32_16x16x32_bf16(a_hi[0], b_hi, acc0, 0, 0, 0);
        acc1 = __builtin_amdgcn_mfma_f32_16x16x32_bf16(a_hi[1], b_hi, acc1, 0, 0, 0);
        acc0 = __builtin_amdgcn_mfma_f32_16x16x32_bf16(a_hi[0], b_lo, acc0, 0, 0, 0);
        acc1 = __builtin_amdgcn_mfma_f32_16x16x32_bf16(a_hi[1], b_lo, acc1, 0, 0, 0);
        acc0 = __builtin_amdgcn_mfma_f32_16x16x32_bf16(a_lo[0], b_hi, acc0, 0, 0, 0);
        acc1 = __builtin_amdgcn_mfma_f32_16x16x32_bf16(a_lo[1], b_hi, acc1, 0, 0, 0);
        acc0 = __builtin_amdgcn_mfma_f32_16x16x32_bf16(a_lo[0], b_lo, acc0, 0, 0, 0);
        acc1 = __builtin_amdgcn_mfma_f32_16x16x32_bf16(a_lo[1], b_lo, acc1, 0, 0, 0);
#pragma unroll
        for (int r = 0; r < 4; ++r) {
            if (acc0[r] < best[0][r]) { best[0][r] = acc0[r]; bt[0][r] = t; }
            if (acc1[r] < best[1][r]) { best[1][r] = acc1[r]; bt[1][r] = t; }
        }
    }

    // reduce across the 16 lanes (cols) per query row, then one atomicMin per query
#pragma unroll
    for (int qq = 0; qq < 2; ++qq)
#pragma unroll
        for (int r = 0; r < 4; ++r) {
            float d = best[qq][r];
            int code = chunk * CODES_PER_CH + (bt[qq][r] << 4) + (lane & 15);
#pragma unroll
            for (int m = 1; m < 16; m <<= 1) {
                float od = __shfl_xor(d, m, 64);
                int oc = __shfl_xor(code, m, 64);
                if (od < d || (od == d && oc < code)) { d = od; code = oc; }
            }
            if ((lane & 15) == 0) {
                int row = ((lane >> 4) * 4) + r;
                int n = (strip * 2 + qq) * 16 + row;
                unsigned bits = __float_as_uint(d);
                unsigned s = ((int)bits >= 0) ? (bits | 0x80000000u) : ~bits;
                unsigned long long key = ((unsigned long long)s << 32) | (unsigned)code;
                atomicMin(&keys[n], key);
            }
        }
}

// ---------------- counts + compact idx ----------------
__global__ __launch_bounds__(256) void k_gather(const unsigned long long* __restrict__ keys,
                                                int* __restrict__ counts,
                                                ushort* __restrict__ idx16) {
    int n = blockIdx.x * 256 + threadIdx.x;
    unsigned long long k = keys[n];
    unsigned idx = (unsigned)(k & 0xFFFFFFFFu);
    atomicAdd(&counts[idx], 1);
    idx16[n] = (ushort)idx;
}

// ---------------- conv3x3 residual + fhat + loss partials (gathers emb by idx) ----------------
__global__ __launch_bounds__(256) void k_conv(const ushort* __restrict__ idx16,
                                              const float* __restrict__ emb,
                                              const float* __restrict__ wp,
                                              const float* __restrict__ bias,
                                              const float* __restrict__ f,
                                              float* __restrict__ out,
                                              float* __restrict__ lpart) {
    __shared__ float sZ[320 * 33];  // 10 rows x 32 cols, 33-float pixel stride (bank pad)
    __shared__ float red[256];
    int blk = blockIdx.x;
    int b = blk >> 2;
    int r0 = (blk & 3) * 8;
    int tid = threadIdx.x;

    for (int i = tid; i < 320; i += 256) {
        int row = i >> 5, col = i & 31;
        int gy = r0 - 1 + row;
        float4* d = reinterpret_cast<float4*>(&sZ[i * 33]);
        if (gy >= 0 && gy < 32) {
            int id = idx16[b * HW + gy * 32 + col];
            const float4* s = reinterpret_cast<const float4*>(emb + id * C);
#pragma unroll
            for (int k = 0; k < 8; ++k) d[k] = s[k];
        } else {
#pragma unroll
            for (int k = 0; k < 8; ++k) d[k] = make_float4(0.f, 0.f, 0.f, 0.f);
        }
    }
    __syncthreads();

    int ty = tid >> 5, tx = tid & 31;
    int gy = r0 + ty;
    float lsum = 0.f;
    for (int co = 0; co < C; co += 8) {
        float acc[8];
#pragma unroll
        for (int u = 0; u < 8; ++u) acc[u] = bias[co + u];
        for (int dy = -1; dy <= 1; ++dy) {
            for (int dx = -1; dx <= 1; ++dx) {
                int gx = tx + dx;
                if (gx < 0 || gx >= 32) continue;  // horizontal zero-pad
                const float* zp = &sZ[((ty + 1 + dy) * 32 + gx) * 33];
                int tap = (dy + 1) * 3 + (dx + 1);
                const float* wtap = &wp[tap * C * C + co];
#pragma unroll
                for (int cin = 0; cin < C; ++cin) {
                    float z = zp[cin];
                    const float* wrow = wtap + cin * C;
#pragma unroll
                    for (int u = 0; u < 8; ++u) acc[u] = fmaf(z, wrow[u], acc[u]);
                }
            }
        }
#pragma unroll
        for (int u = 0; u < 8; ++u) {
            int cc = co + u;
            float zqv = sZ[((ty + 1) * 32 + tx) * 33 + cc];
            float fh = 0.5f * (zqv + acc[u]);  // h*(1-r) + (conv+b)*r, r=0.5
            int off = (b * C + cc) * HW + gy * 32 + tx;
            out[off] = fh;
            float diff = fh - f[off];
            lsum += diff * diff;
        }
    }
    red[tid] = lsum;
    __syncthreads();
    for (int s = 128; s > 0; s >>= 1) {
        if (tid < s) red[tid] += red[tid + s];
        __syncthreads();
    }
    if (tid == 0) lpart[blockIdx.x] = red[0];
}

// ---------------- scalars ----------------
__global__ __launch_bounds__(256) void k_final(const float* __restrict__ lpart,
                                               const int* __restrict__ counts,
                                               float* __restrict__ out) {
    __shared__ float red[256];
    __shared__ int redi[256];
    int tid = threadIdx.x;
    int used = 0;
    for (int i = tid; i < VOCAB; i += 256) used += (counts[i] != 0) ? 1 : 0;
    red[tid] = (tid < 64) ? lpart[tid] : 0.f;
    redi[tid] = used;
    __syncthreads();
    for (int s = 128; s > 0; s >>= 1) {
        if (tid < s) { red[tid] += red[tid + s]; redi[tid] += redi[tid + s]; }
        __syncthreads();
    }
    if (tid == 0) {
        out[N_Q * C]     = 1.25f * red[0] / (float)(N_Q * C);      // (1+BETA)*MSE
        out[N_Q * C + 1] = 100.f * (float)redi[0] / (float)VOCAB;  // counts>=1 <=> prob>0.01/V
    }
}

extern "C" void kernel_launch(void* const* d_in, const int* in_sizes, int n_in,
                              void* d_out, int out_size, void* d_ws, size_t ws_size,
                              hipStream_t stream) {
    const float* f     = (const float*)d_in[0];
    const float* emb   = (const float*)d_in[1];
    const float* convw = (const float*)d_in[2];
    const float* convb = (const float*)d_in[3];
    float* out = (float*)d_out;
    float* ws  = (float*)d_ws;

    // float-unit offsets into ws (total 1,131,584 floats ~= 4.53 MB)
    float*  enorm2 = ws;                              // 16384
    float*  wp     = ws + 16384;                      // 9216
    float*  lpart  = ws + 25600;                      // 64
    int*    counts = (int*)(ws + 25664);              // 16384
    ushort* idx16  = (ushort*)(ws + 42048);           // 16384 ushorts
    unsigned long long* keys = (unsigned long long*)(ws + 50240);  // 16384 u64 (8B-aligned)
    ushort* Qhi    = (ushort*)(ws + 83008);           // 524288 ushorts
    ushort* Qlo    = (ushort*)(ws + 345152);
    ushort* Ehi    = (ushort*)(ws + 607296);
    ushort* Elo    = (ushort*)(ws + 869440);

    hipMemsetAsync(keys, 0xFF, VOCAB * sizeof(unsigned long long), stream);
    hipMemsetAsync(counts, 0, VOCAB * sizeof(int), stream);
    k_prepE<<<VOCAB / 256, 256, 0, stream>>>(emb, enorm2, Ehi, Elo);
    k_packQ<<<256, 256, 0, stream>>>(f, Qhi, Qlo);
    k_wpack<<<(C * C * 9 + 255) / 256, 256, 0, stream>>>(convw, wp);
    dim3 g2(128, VCH);
    k_argmin<<<g2, 256, 0, stream>>>(Qhi, Qlo, Ehi, Elo, enorm2, keys);
    k_gather<<<N_Q / 256, 256, 0, stream>>>(keys, counts, idx16);
    k_conv<<<64, 256, 0, stream>>>(idx16, emb, wp, convb, f, out, lpart);
    k_final<<<1, 256, 0, stream>>>(lpart, counts, out);
}

// Round 8
// 123.147 us; speedup vs baseline: 3.8937x; 1.2473x over previous
//
#include <hip/hip_runtime.h>

#define VOCAB 16384
#define N_Q   16384   // B*h*w = 16*32*32
#define C     32
#define HW    1024    // h*w
#define VCH   16
#define CODES_PER_CH (VOCAB / VCH)        // 1024
#define TILES_PER_CH (CODES_PER_CH / 16)  // 64

typedef short short8 __attribute__((ext_vector_type(8)));
typedef float f32x4  __attribute__((ext_vector_type(4)));

__device__ inline ushort f2bf_rne(float x) {
    unsigned u = __float_as_uint(x);
    unsigned r = u + 0x7FFFu + ((u >> 16) & 1u);
    return (ushort)(r >> 16);
}
__device__ inline float bf2f(ushort h) { return __uint_as_float(((unsigned)h) << 16); }

// ---- fused: E -> bf16 hi/lo B-frags + ||e||^2/2 quad-broadcast + conv wpack ----
// frag layout (HW-verified r6/r7): tile tg=j>>4, lane=(ko<<4)|(j&15), elem 0..7
__global__ __launch_bounds__(256) void k_prepE(const float* __restrict__ emb,
                                               float* __restrict__ enq,
                                               ushort* __restrict__ hi, ushort* __restrict__ lo,
                                               const float* __restrict__ convw,
                                               float* __restrict__ wp) {
    if (blockIdx.x == 64) {  // conv-weight repack to [tap][cin][cout]
        for (int k = threadIdx.x; k < C * C * 9; k += 256) {
            int cout = k / (C * 9);
            int r = k % (C * 9);
            int cin = r / 9;
            int tap = r % 9;
            wp[(tap * C + cin) * C + cout] = convw[k];
        }
        return;
    }
    int j = blockIdx.x * 256 + threadIdx.x;   // code row, exact 16384
    const float4* e4 = reinterpret_cast<const float4*>(emb + j * C);
    float s = 0.f;
    float v[C];
#pragma unroll
    for (int k = 0; k < 8; ++k) {
        float4 t = e4[k];
        v[4 * k] = t.x; v[4 * k + 1] = t.y; v[4 * k + 2] = t.z; v[4 * k + 3] = t.w;
        s += t.x * t.x + t.y * t.y + t.z * t.z + t.w * t.w;
    }
    float en2 = 0.5f * s;
    float4 q = make_float4(en2, en2, en2, en2);
    *reinterpret_cast<float4*>(enq + j * 4) = q;
#pragma unroll
    for (int ko = 0; ko < 4; ++ko) {
        short8 sh, sl;
#pragma unroll
        for (int e = 0; e < 8; ++e) {
            float x = v[ko * 8 + e];
            ushort h = f2bf_rne(x);
            sh[e] = (short)h;
            sl[e] = (short)f2bf_rne(x - bf2f(h));
        }
        int off = (j >> 4) * 512 + (((ko << 4) | (j & 15)) * 8);
        *reinterpret_cast<short8*>(hi + off) = sh;
        *reinterpret_cast<short8*>(lo + off) = sl;
    }
}

// ---- pack Q (NCHW f) -> NEGATED bf16 hi/lo A-frags; fused keys/counts init ----
__global__ __launch_bounds__(256) void k_packQ(const float* __restrict__ f,
                                               ushort* __restrict__ hi, ushort* __restrict__ lo,
                                               unsigned long long* __restrict__ keys,
                                               int* __restrict__ counts) {
    int i = blockIdx.x * 256 + threadIdx.x;   // 65536: (n fast, c-octet slow)
    int n = i & (N_Q - 1);
    int co = i >> 14;  // 0..3
    if (co == 0) keys[n] = ~0ULL;
    if (co == 1) counts[n] = 0;   // VOCAB == N_Q
    int b = n >> 10, rem = n & 1023;
    short8 sh, sl;
#pragma unroll
    for (int e = 0; e < 8; ++e) {
        int c = co * 8 + e;
        float x = -f[(b * C + c) * HW + rem];   // negated
        ushort h = f2bf_rne(x);
        sh[e] = (short)h;
        sl[e] = (short)f2bf_rne(x - bf2f(h));
    }
    int off = (n >> 4) * 512 + (((co << 4) | (n & 15)) * 8);
    *reinterpret_cast<short8*>(hi + off) = sh;
    *reinterpret_cast<short8*>(lo + off) = sl;
}

// ---- MFMA argmin: d' = ||e||^2/2 - q.e via C-operand enq; 128 queries/wave ----
__global__ __launch_bounds__(256, 2) void k_argmin(
    const ushort* __restrict__ Qhi, const ushort* __restrict__ Qlo,
    const ushort* __restrict__ Ehi, const ushort* __restrict__ Elo,
    const float* __restrict__ enq,
    unsigned long long* __restrict__ keys) {
    int tid = threadIdx.x;
    int lane = tid & 63;
    int w = tid >> 6;
    int wid = blockIdx.x * 4 + w;        // 0..127 -> 128 queries each
    int chunk = blockIdx.y;              // 0..15

    short8 a_hi[8], a_lo[8];
#pragma unroll
    for (int qq = 0; qq < 8; ++qq) {
        int ss = wid * 8 + qq;           // substrip of 16 queries
        a_hi[qq] = *reinterpret_cast<const short8*>(Qhi + ss * 512 + lane * 8);
        a_lo[qq] = *reinterpret_cast<const short8*>(Qlo + ss * 512 + lane * 8);
    }
    float best[8][4];
    int   bt[8][4];
#pragma unroll
    for (int qq = 0; qq < 8; ++qq)
#pragma unroll
        for (int r = 0; r < 4; ++r) { best[qq][r] = 3.4e38f; bt[qq][r] = 0; }

    const short8* pe_hi = reinterpret_cast<const short8*>(Ehi) + (size_t)chunk * TILES_PER_CH * 64 + lane;
    const short8* pe_lo = reinterpret_cast<const short8*>(Elo) + (size_t)chunk * TILES_PER_CH * 64 + lane;
    const f32x4*  penq  = reinterpret_cast<const f32x4*>(enq) + chunk * CODES_PER_CH + (lane & 15);

    for (int t = 0; t < TILES_PER_CH; ++t) {
        short8 b_hi = pe_hi[t * 64];
        short8 b_lo = pe_lo[t * 64];
        f32x4  eq   = penq[t * 16];
#pragma unroll
        for (int qq = 0; qq < 8; ++qq) {
            f32x4 acc = __builtin_amdgcn_mfma_f32_16x16x32_bf16(a_hi[qq], b_hi, eq, 0, 0, 0);
            acc = __builtin_amdgcn_mfma_f32_16x16x32_bf16(a_hi[qq], b_lo, acc, 0, 0, 0);
            acc = __builtin_amdgcn_mfma_f32_16x16x32_bf16(a_lo[qq], b_hi, acc, 0, 0, 0);
            acc = __builtin_amdgcn_mfma_f32_16x16x32_bf16(a_lo[qq], b_lo, acc, 0, 0, 0);
#pragma unroll
            for (int r = 0; r < 4; ++r) {
                if (acc[r] < best[qq][r]) { best[qq][r] = acc[r]; bt[qq][r] = t; }
            }
        }
    }

    // 16-lane column reduce per query row, then one atomicMin per query
#pragma unroll
    for (int qq = 0; qq < 8; ++qq)
#pragma unroll
        for (int r = 0; r < 4; ++r) {
            float d = best[qq][r];
            int code = chunk * CODES_PER_CH + (bt[qq][r] << 4) + (lane & 15);
#pragma unroll
            for (int m = 1; m < 16; m <<= 1) {
                float od = __shfl_xor(d, m, 64);
                int oc = __shfl_xor(code, m, 64);
                if (od < d || (od == d && oc < code)) { d = od; code = oc; }
            }
            if ((lane & 15) == 0) {
                int row = ((lane >> 4) * 4) + r;
                int n = (wid * 8 + qq) * 16 + row;
                unsigned bits = __float_as_uint(d);
                unsigned s = ((int)bits >= 0) ? (bits | 0x80000000u) : ~bits;
                unsigned long long key = ((unsigned long long)s << 32) | (unsigned)code;
                atomicMin(&keys[n], key);
            }
        }
}

// ---- conv3x3 residual + fhat + loss partials + bincount (keys-direct gather) ----
// 256 blocks: (b, 2-row tile). 256 thr = (cg 0..3, ty 0..1, tx 0..31); 8 couts/thread
__global__ __launch_bounds__(256) void k_conv(const unsigned long long* __restrict__ keys,
                                              const float* __restrict__ emb,
                                              const float* __restrict__ wp,
                                              const float* __restrict__ bias,
                                              const float* __restrict__ f,
                                              int* __restrict__ counts,
                                              float* __restrict__ out,
                                              float* __restrict__ lpart) {
    __shared__ float sZ[128 * 33];   // 4 rows x 32 cols, 33-float pixel stride
    __shared__ float red[256];
    int blk = blockIdx.x;
    int b = blk >> 4;
    int r0 = (blk & 15) * 2;
    int tid = threadIdx.x;

    {   // stage 4 rows (r0-1..r0+2): 128 px x 2 half-rows of channels
        int px = tid >> 1, half = tid & 1;
        int row = px >> 5, col = px & 31;
        int gy = r0 - 1 + row;
        float* d = &sZ[px * 33 + half * 16];
        if (gy >= 0 && gy < 32) {
            int id = (int)(keys[b * HW + gy * 32 + col] & 0xFFFFFFFFULL);
            const float4* s = reinterpret_cast<const float4*>(emb + id * C + half * 16);
#pragma unroll
            for (int k = 0; k < 4; ++k) {
                float4 v = s[k];
                d[4 * k] = v.x; d[4 * k + 1] = v.y; d[4 * k + 2] = v.z; d[4 * k + 3] = v.w;
            }
        } else {
#pragma unroll
            for (int k = 0; k < 16; ++k) d[k] = 0.f;
        }
    }
    __syncthreads();

    int tx = tid & 31, ty = (tid >> 5) & 1, cg = tid >> 6;
    int co0 = cg * 8;
    int gy = r0 + ty;
    if (cg == 0) {  // bincount: each real px once
        int id = (int)(keys[b * HW + gy * 32 + tx] & 0xFFFFFFFFULL);
        atomicAdd(&counts[id], 1);
    }
    float acc[8];
#pragma unroll
    for (int u = 0; u < 8; ++u) acc[u] = bias[co0 + u];
    for (int dy = -1; dy <= 1; ++dy) {
        for (int dx = -1; dx <= 1; ++dx) {
            int gx = tx + dx;
            if (gx < 0 || gx >= 32) continue;
            const float* zp = &sZ[((ty + 1 + dy) * 32 + gx) * 33];
            int tap = (dy + 1) * 3 + (dx + 1);
            const float* wtap = &wp[tap * C * C + co0];
#pragma unroll
            for (int cin = 0; cin < C; ++cin) {
                float z = zp[cin];
                const float* wrow = wtap + cin * C;
#pragma unroll
                for (int u = 0; u < 8; ++u) acc[u] = fmaf(z, wrow[u], acc[u]);
            }
        }
    }
    float lsum = 0.f;
#pragma unroll
    for (int u = 0; u < 8; ++u) {
        int cc = co0 + u;
        float zqv = sZ[((ty + 1) * 32 + tx) * 33 + cc];
        float fh = 0.5f * (zqv + acc[u]);   // h*(1-r) + (conv+b)*r, r=0.5
        int off = (b * C + cc) * HW + gy * 32 + tx;
        out[off] = fh;
        float diff = fh - f[off];
        lsum += diff * diff;
    }
    red[tid] = lsum;
    __syncthreads();
    for (int s = 128; s > 0; s >>= 1) {
        if (tid < s) red[tid] += red[tid + s];
        __syncthreads();
    }
    if (tid == 0) lpart[blk] = red[0];
}

// ---- scalars ----
__global__ __launch_bounds__(256) void k_final(const float* __restrict__ lpart,
                                               const int* __restrict__ counts,
                                               float* __restrict__ out) {
    __shared__ float red[256];
    __shared__ int redi[256];
    int tid = threadIdx.x;
    int used = 0;
    for (int i = tid; i < VOCAB; i += 256) used += (counts[i] != 0) ? 1 : 0;
    red[tid] = lpart[tid];
    redi[tid] = used;
    __syncthreads();
    for (int s = 128; s > 0; s >>= 1) {
        if (tid < s) { red[tid] += red[tid + s]; redi[tid] += redi[tid + s]; }
        __syncthreads();
    }
    if (tid == 0) {
        out[N_Q * C]     = 1.25f * red[0] / (float)(N_Q * C);      // (1+BETA)*MSE
        out[N_Q * C + 1] = 100.f * (float)redi[0] / (float)VOCAB;  // counts>=1
    }
}

extern "C" void kernel_launch(void* const* d_in, const int* in_sizes, int n_in,
                              void* d_out, int out_size, void* d_ws, size_t ws_size,
                              hipStream_t stream) {
    const float* f     = (const float*)d_in[0];
    const float* emb   = (const float*)d_in[1];
    const float* convw = (const float*)d_in[2];
    const float* convb = (const float*)d_in[3];
    float* out = (float*)d_out;
    float* ws  = (float*)d_ws;

    // float-unit offsets into ws (total ~4.7 MB)
    float*  wp     = ws;                              // 9216
    float*  lpart  = ws + 9216;                       // 256
    int*    counts = (int*)(ws + 9472);               // 16384
    unsigned long long* keys = (unsigned long long*)(ws + 25856);  // 16384 u64 (8B-aligned)
    float*  enq    = ws + 58624;                      // 65536 (quad-broadcast ||e||^2/2)
    ushort* Qhi    = (ushort*)(ws + 124160);          // 524288 ushorts each
    ushort* Qlo    = (ushort*)(ws + 386304);
    ushort* Ehi    = (ushort*)(ws + 648448);
    ushort* Elo    = (ushort*)(ws + 910592);

    k_prepE<<<65, 256, 0, stream>>>(emb, enq, Ehi, Elo, convw, wp);
    k_packQ<<<256, 256, 0, stream>>>(f, Qhi, Qlo, keys, counts);
    dim3 g2(32, VCH);
    k_argmin<<<g2, 256, 0, stream>>>(Qhi, Qlo, Ehi, Elo, enq, keys);
    k_conv<<<256, 256, 0, stream>>>(keys, emb, wp, convb, f, counts, out, lpart);
    k_final<<<1, 256, 0, stream>>>(lpart, counts, out);
}

// Round 9
// 100.597 us; speedup vs baseline: 4.7666x; 1.2242x over previous
//
#include <hip/hip_runtime.h>

#define VOCAB 16384
#define N_Q   16384   // B*h*w = 16*32*32
#define C     32
#define HW    1024    // h*w
#define VCH   16
#define CODES_PER_CH 1024
#define TILES_PER_CH 64
#define GRP    8          // tiles per staging group
#define NGRP   8          // groups per chunk
#define GBYTES 18432      // 8KB hi + 8KB lo + 2KB enq

typedef _Float16 half8 __attribute__((ext_vector_type(8)));
typedef float f32x4  __attribute__((ext_vector_type(4)));

// ---- fused prep: E -> f16 hi/lo B-frags + ||e||^2/2 quads + wpack + keys/counts init ----
// frag layout (HW-verified r6-r8): tile tg=j>>4, lane=(ko<<4)|(j&15), elem 0..7
__global__ __launch_bounds__(256) void k_prepE(const float* __restrict__ emb,
                                               float* __restrict__ enq,
                                               _Float16* __restrict__ hi, _Float16* __restrict__ lo,
                                               const float* __restrict__ convw,
                                               float* __restrict__ wp,
                                               unsigned long long* __restrict__ keys,
                                               int* __restrict__ counts) {
    int bx = blockIdx.x;
    if (bx >= 64) {
        if (bx == 64) {          // conv-weight repack to [tap][cin][cout]
            for (int k = threadIdx.x; k < C * C * 9; k += 256) {
                int cout = k / (C * 9);
                int r = k % (C * 9);
                int cin = r / 9;
                int tap = r % 9;
                wp[(tap * C + cin) * C + cout] = convw[k];
            }
        } else if (bx == 65) {
            for (int k = threadIdx.x; k < VOCAB; k += 256) keys[k] = ~0ULL;
        } else {
            for (int k = threadIdx.x; k < VOCAB; k += 256) counts[k] = 0;
        }
        return;
    }
    int j = bx * 256 + threadIdx.x;   // code row
    const float4* e4 = reinterpret_cast<const float4*>(emb + j * C);
    float s = 0.f;
    float v[C];
#pragma unroll
    for (int k = 0; k < 8; ++k) {
        float4 t = e4[k];
        v[4 * k] = t.x; v[4 * k + 1] = t.y; v[4 * k + 2] = t.z; v[4 * k + 3] = t.w;
        s += t.x * t.x + t.y * t.y + t.z * t.z + t.w * t.w;
    }
    float en2 = 0.5f * s;
    *reinterpret_cast<float4*>(enq + j * 4) = make_float4(en2, en2, en2, en2);
#pragma unroll
    for (int ko = 0; ko < 4; ++ko) {
        half8 vh, vl;
#pragma unroll
        for (int e = 0; e < 8; ++e) {
            float x = v[ko * 8 + e];
            _Float16 h = (_Float16)x;
            vh[e] = h;
            vl[e] = (_Float16)(x - (float)h);
        }
        int off = (j >> 4) * 512 + (((ko << 4) | (j & 15)) * 8);
        *reinterpret_cast<half8*>(hi + off) = vh;
        *reinterpret_cast<half8*>(lo + off) = vl;
    }
}

// ---- staging: one 18KB group (8 tiles) -> LDS via global_load_lds(16B) ----
__device__ __forceinline__ void stage_grp(const char* ehib, const char* elob, const char* enqb,
                                          char* db, int chunk, int g, int w, int lane) {
#pragma unroll
    for (int k = 0; k < 5; ++k) {
        int widx = w + 4 * k;     // 18 wave-copies of 1KB, split over 4 waves
        if (widx < 18) {
            const char* src;
            if (widx < 8)
                src = ehib + ((size_t)(chunk * TILES_PER_CH + g * GRP + widx) << 10);
            else if (widx < 16)
                src = elob + ((size_t)(chunk * TILES_PER_CH + g * GRP + widx - 8) << 10);
            else
                src = enqb + ((size_t)chunk * 16384 + (size_t)g * 2048 + (size_t)(widx - 16) * 1024);
            __builtin_amdgcn_global_load_lds(
                (const __attribute__((address_space(1))) void*)(src + lane * 16),
                (__attribute__((address_space(3))) void*)(db + widx * 1024 + lane * 16),
                16, 0, 0);
        }
    }
}

// ---- MFMA argmin: d' = ||e||^2/2 - q.e ; f16 3-way split; LDS-shared E ----
// block = 4 waves x 64 queries = 256 queries; grid (64, 16 chunks)
__global__ __launch_bounds__(256, 4) void k_argmin(
    const float* __restrict__ f,
    const _Float16* __restrict__ Ehi, const _Float16* __restrict__ Elo,
    const float* __restrict__ enq,
    unsigned long long* __restrict__ keys) {
    __shared__ __align__(16) char lds[2 * GBYTES];
    int tid = threadIdx.x;
    int lane = tid & 63;
    int w = tid >> 6;
    int wid = blockIdx.x * 4 + w;        // 0..255, 64 queries each
    int chunk = blockIdx.y;

    // Q prologue: load 64 queries from f (NCHW), negate, f16 hi/lo split
    half8 a_hi[4], a_lo[4];
    int c0 = (lane >> 4) * 8;
#pragma unroll
    for (int qq = 0; qq < 4; ++qq) {
        int n = (wid * 4 + qq) * 16 + (lane & 15);
        int b = n >> 10, rem = n & 1023;
        const float* fp = f + (b * C + c0) * HW + rem;
#pragma unroll
        for (int e = 0; e < 8; ++e) {
            float x = -fp[e * HW];            // negated
            _Float16 h = (_Float16)x;
            a_hi[qq][e] = h;
            a_lo[qq][e] = (_Float16)(x - (float)h);
        }
    }

    float best[4][4];
    int   bt[4][4];
#pragma unroll
    for (int qq = 0; qq < 4; ++qq)
#pragma unroll
        for (int r = 0; r < 4; ++r) { best[qq][r] = 3.4e38f; bt[qq][r] = 0; }

    const char* ehib = (const char*)Ehi;
    const char* elob = (const char*)Elo;
    const char* enqb = (const char*)enq;

    stage_grp(ehib, elob, enqb, lds, chunk, 0, w, lane);
    __syncthreads();   // drains vmcnt(0): group 0 resident

    for (int g = 0; g < NGRP; ++g) {
        if (g + 1 < NGRP)
            stage_grp(ehib, elob, enqb, lds + ((g + 1) & 1) * GBYTES, chunk, g + 1, w, lane);
        const char* bb = lds + (g & 1) * GBYTES;
#pragma unroll
        for (int tt = 0; tt < GRP; ++tt) {
            half8 bh = *(const half8*)(bb + tt * 1024 + lane * 16);
            half8 bl = *(const half8*)(bb + 8192 + tt * 1024 + lane * 16);
            f32x4 eq = *(const f32x4*)(bb + 16384 + tt * 256 + (lane & 15) * 16);
#pragma unroll
            for (int qq = 0; qq < 4; ++qq) {
                f32x4 acc = __builtin_amdgcn_mfma_f32_16x16x32_f16(a_hi[qq], bh, eq, 0, 0, 0);
                acc = __builtin_amdgcn_mfma_f32_16x16x32_f16(a_hi[qq], bl, acc, 0, 0, 0);
                acc = __builtin_amdgcn_mfma_f32_16x16x32_f16(a_lo[qq], bh, acc, 0, 0, 0);
#pragma unroll
                for (int r = 0; r < 4; ++r) {
                    if (acc[r] < best[qq][r]) { best[qq][r] = acc[r]; bt[qq][r] = g * GRP + tt; }
                }
            }
        }
        __syncthreads();   // all waves done with buf[g&1]; next stage drained
    }

    // 16-lane column reduce per query row, then one atomicMin per query
#pragma unroll
    for (int qq = 0; qq < 4; ++qq)
#pragma unroll
        for (int r = 0; r < 4; ++r) {
            float d = best[qq][r];
            int code = chunk * CODES_PER_CH + (bt[qq][r] << 4) + (lane & 15);
#pragma unroll
            for (int m = 1; m < 16; m <<= 1) {
                float od = __shfl_xor(d, m, 64);
                int oc = __shfl_xor(code, m, 64);
                if (od < d || (od == d && oc < code)) { d = od; code = oc; }
            }
            if ((lane & 15) == 0) {
                int row = ((lane >> 4) * 4) + r;
                int n = (wid * 4 + qq) * 16 + row;
                unsigned bits = __float_as_uint(d);
                unsigned s = ((int)bits >= 0) ? (bits | 0x80000000u) : ~bits;
                unsigned long long key = ((unsigned long long)s << 32) | (unsigned)code;
                atomicMin(&keys[n], key);
            }
        }
}

// ---- conv3x3 residual + fhat + loss partials + bincount (keys-direct gather) ----
__global__ __launch_bounds__(256) void k_conv(const unsigned long long* __restrict__ keys,
                                              const float* __restrict__ emb,
                                              const float* __restrict__ wp,
                                              const float* __restrict__ bias,
                                              const float* __restrict__ f,
                                              int* __restrict__ counts,
                                              float* __restrict__ out,
                                              float* __restrict__ lpart) {
    __shared__ float sZ[128 * 33];
    __shared__ float red[256];
    int blk = blockIdx.x;
    int b = blk >> 4;
    int r0 = (blk & 15) * 2;
    int tid = threadIdx.x;

    {
        int px = tid >> 1, half = tid & 1;
        int row = px >> 5, col = px & 31;
        int gy = r0 - 1 + row;
        float* d = &sZ[px * 33 + half * 16];
        if (gy >= 0 && gy < 32) {
            int id = (int)(keys[b * HW + gy * 32 + col] & 0xFFFFFFFFULL);
            const float4* s = reinterpret_cast<const float4*>(emb + id * C + half * 16);
#pragma unroll
            for (int k = 0; k < 4; ++k) {
                float4 v = s[k];
                d[4 * k] = v.x; d[4 * k + 1] = v.y; d[4 * k + 2] = v.z; d[4 * k + 3] = v.w;
            }
        } else {
#pragma unroll
            for (int k = 0; k < 16; ++k) d[k] = 0.f;
        }
    }
    __syncthreads();

    int tx = tid & 31, ty = (tid >> 5) & 1, cg = tid >> 6;
    int co0 = cg * 8;
    int gy = r0 + ty;
    if (cg == 0) {
        int id = (int)(keys[b * HW + gy * 32 + tx] & 0xFFFFFFFFULL);
        atomicAdd(&counts[id], 1);
    }
    float acc[8];
#pragma unroll
    for (int u = 0; u < 8; ++u) acc[u] = bias[co0 + u];
    for (int dy = -1; dy <= 1; ++dy) {
        for (int dx = -1; dx <= 1; ++dx) {
            int gx = tx + dx;
            if (gx < 0 || gx >= 32) continue;
            const float* zp = &sZ[((ty + 1 + dy) * 32 + gx) * 33];
            int tap = (dy + 1) * 3 + (dx + 1);
            const float* wtap = &wp[tap * C * C + co0];
#pragma unroll
            for (int cin = 0; cin < C; ++cin) {
                float z = zp[cin];
                const float* wrow = wtap + cin * C;
#pragma unroll
                for (int u = 0; u < 8; ++u) acc[u] = fmaf(z, wrow[u], acc[u]);
            }
        }
    }
    float lsum = 0.f;
#pragma unroll
    for (int u = 0; u < 8; ++u) {
        int cc = co0 + u;
        float zqv = sZ[((ty + 1) * 32 + tx) * 33 + cc];
        float fh = 0.5f * (zqv + acc[u]);   // h*(1-r) + (conv+b)*r, r=0.5
        int off = (b * C + cc) * HW + gy * 32 + tx;
        out[off] = fh;
        float diff = fh - f[off];
        lsum += diff * diff;
    }
    red[tid] = lsum;
    __syncthreads();
    for (int s = 128; s > 0; s >>= 1) {
        if (tid < s) red[tid] += red[tid + s];
        __syncthreads();
    }
    if (tid == 0) lpart[blk] = red[0];
}

// ---- scalars ----
__global__ __launch_bounds__(256) void k_final(const float* __restrict__ lpart,
                                               const int* __restrict__ counts,
                                               float* __restrict__ out) {
    __shared__ float red[256];
    __shared__ int redi[256];
    int tid = threadIdx.x;
    int used = 0;
    for (int i = tid; i < VOCAB; i += 256) used += (counts[i] != 0) ? 1 : 0;
    red[tid] = lpart[tid];
    redi[tid] = used;
    __syncthreads();
    for (int s = 128; s > 0; s >>= 1) {
        if (tid < s) { red[tid] += red[tid + s]; redi[tid] += redi[tid + s]; }
        __syncthreads();
    }
    if (tid == 0) {
        out[N_Q * C]     = 1.25f * red[0] / (float)(N_Q * C);      // (1+BETA)*MSE
        out[N_Q * C + 1] = 100.f * (float)redi[0] / (float)VOCAB;  // counts>=1
    }
}

extern "C" void kernel_launch(void* const* d_in, const int* in_sizes, int n_in,
                              void* d_out, int out_size, void* d_ws, size_t ws_size,
                              hipStream_t stream) {
    const float* f     = (const float*)d_in[0];
    const float* emb   = (const float*)d_in[1];
    const float* convw = (const float*)d_in[2];
    const float* convb = (const float*)d_in[3];
    float* out = (float*)d_out;
    float* ws  = (float*)d_ws;

    // float-unit offsets (total 648,448 floats ~= 2.6 MB)
    float*  wp     = ws;                              // 9216
    float*  lpart  = ws + 9216;                       // 256
    int*    counts = (int*)(ws + 9472);               // 16384
    unsigned long long* keys = (unsigned long long*)(ws + 25856);  // 16384 u64
    float*  enq    = ws + 58624;                      // 65536 (quad ||e||^2/2)
    _Float16* Ehi  = (_Float16*)(ws + 124160);        // 524288 halves
    _Float16* Elo  = (_Float16*)(ws + 386304);        // 524288 halves

    k_prepE<<<67, 256, 0, stream>>>(emb, enq, Ehi, Elo, convw, wp, keys, counts);
    dim3 g2(64, VCH);
    k_argmin<<<g2, 256, 0, stream>>>(f, Ehi, Elo, enq, keys);
    k_conv<<<256, 256, 0, stream>>>(keys, emb, wp, convb, f, counts, out, lpart);
    k_final<<<1, 256, 0, stream>>>(lpart, counts, out);
}

// Round 10
// 91.942 us; speedup vs baseline: 5.2153x; 1.0941x over previous
//
#include <hip/hip_runtime.h>

#define VOCAB 16384
#define N_Q   16384   // B*h*w = 16*32*32
#define C     32
#define HW    1024    // h*w
#define VCH   16
#define CODES_PER_CH 1024
#define TILES_PER_CH 64
#define GRP    8          // tiles per staging group
#define NGRP   8          // groups per chunk
#define GBYTES 18432      // 8KB hi + 8KB lo + 2KB enq

typedef _Float16 half8 __attribute__((ext_vector_type(8)));
typedef float f32x4  __attribute__((ext_vector_type(4)));

// ---- fused prep: E -> f16 hi/lo B-frags + ||e||^2/2 quads + wpack + keys/counts init ----
// frag layout (HW-verified r6-r9): tile tg=j>>4, lane=(ko<<4)|(j&15), elem 0..7
__global__ __launch_bounds__(256) void k_prepE(const float* __restrict__ emb,
                                               float* __restrict__ enq,
                                               _Float16* __restrict__ hi, _Float16* __restrict__ lo,
                                               const float* __restrict__ convw,
                                               float* __restrict__ wp,
                                               unsigned long long* __restrict__ keys,
                                               int* __restrict__ counts) {
    int bx = blockIdx.x;
    if (bx >= 64) {
        if (bx == 64) {          // conv-weight repack to [tap][cin][cout]
            for (int k = threadIdx.x; k < C * C * 9; k += 256) {
                int cout = k / (C * 9);
                int r = k % (C * 9);
                int cin = r / 9;
                int tap = r % 9;
                wp[(tap * C + cin) * C + cout] = convw[k];
            }
        } else if (bx == 65) {
            for (int k = threadIdx.x; k < VOCAB; k += 256) keys[k] = ~0ULL;
        } else {
            for (int k = threadIdx.x; k < VOCAB; k += 256) counts[k] = 0;
        }
        return;
    }
    int j = bx * 256 + threadIdx.x;   // code row
    const float4* e4 = reinterpret_cast<const float4*>(emb + j * C);
    float s = 0.f;
    float v[C];
#pragma unroll
    for (int k = 0; k < 8; ++k) {
        float4 t = e4[k];
        v[4 * k] = t.x; v[4 * k + 1] = t.y; v[4 * k + 2] = t.z; v[4 * k + 3] = t.w;
        s += t.x * t.x + t.y * t.y + t.z * t.z + t.w * t.w;
    }
    float en2 = 0.5f * s;
    *reinterpret_cast<float4*>(enq + j * 4) = make_float4(en2, en2, en2, en2);
#pragma unroll
    for (int ko = 0; ko < 4; ++ko) {
        half8 vh, vl;
#pragma unroll
        for (int e = 0; e < 8; ++e) {
            float x = v[ko * 8 + e];
            _Float16 h = (_Float16)x;
            vh[e] = h;
            vl[e] = (_Float16)(x - (float)h);
        }
        int off = (j >> 4) * 512 + (((ko << 4) | (j & 15)) * 8);
        *reinterpret_cast<half8*>(hi + off) = vh;
        *reinterpret_cast<half8*>(lo + off) = vl;
    }
}

// ---- staging: one 18KB group (8 tiles) -> LDS via global_load_lds(16B) ----
__device__ __forceinline__ void stage_grp(const char* ehib, const char* elob, const char* enqb,
                                          char* db, int chunk, int g, int w, int lane) {
#pragma unroll
    for (int k = 0; k < 5; ++k) {
        int widx = w + 4 * k;     // 18 wave-copies of 1KB, split over 4 waves
        if (widx < 18) {
            const char* src;
            if (widx < 8)
                src = ehib + ((size_t)(chunk * TILES_PER_CH + g * GRP + widx) << 10);
            else if (widx < 16)
                src = elob + ((size_t)(chunk * TILES_PER_CH + g * GRP + widx - 8) << 10);
            else
                src = enqb + ((size_t)chunk * 16384 + (size_t)g * 2048 + (size_t)(widx - 16) * 1024);
            __builtin_amdgcn_global_load_lds(
                (const __attribute__((address_space(1))) void*)(src + lane * 16),
                (__attribute__((address_space(3))) void*)(db + widx * 1024 + lane * 16),
                16, 0, 0);
        }
    }
}

// ---- MFMA argmin: d' = ||e||^2/2 - q.e ; f16 3-way split; LDS-shared E ----
// block = 4 waves x 64 queries; grid (64, 16 chunks); 4 waves/EU PINNED (128 VGPR budget)
__global__ __attribute__((amdgpu_flat_work_group_size(256, 256), amdgpu_waves_per_eu(4, 4)))
void k_argmin(
    const float* __restrict__ f,
    const _Float16* __restrict__ Ehi, const _Float16* __restrict__ Elo,
    const float* __restrict__ enq,
    unsigned long long* __restrict__ keys) {
    __shared__ __align__(16) char lds[2 * GBYTES];
    int tid = threadIdx.x;
    int lane = tid & 63;
    int w = tid >> 6;
    int wid = blockIdx.x * 4 + w;        // 0..255, 64 queries each
    int chunk = blockIdx.y;

    // Q prologue: load 64 queries from f (NCHW), negate, f16 hi/lo split
    half8 a_hi[4], a_lo[4];
    int c0 = (lane >> 4) * 8;
#pragma unroll
    for (int qq = 0; qq < 4; ++qq) {
        int n = (wid * 4 + qq) * 16 + (lane & 15);
        int b = n >> 10, rem = n & 1023;
        const float* fp = f + (b * C + c0) * HW + rem;
#pragma unroll
        for (int e = 0; e < 8; ++e) {
            float x = -fp[e * HW];            // negated
            _Float16 h = (_Float16)x;
            a_hi[qq][e] = h;
            a_lo[qq][e] = (_Float16)(x - (float)h);
        }
    }

    float best[4][4];
    int   bt[4][4];
#pragma unroll
    for (int qq = 0; qq < 4; ++qq)
#pragma unroll
        for (int r = 0; r < 4; ++r) { best[qq][r] = 3.4e38f; bt[qq][r] = 0; }

    const char* ehib = (const char*)Ehi;
    const char* elob = (const char*)Elo;
    const char* enqb = (const char*)enq;

    stage_grp(ehib, elob, enqb, lds, chunk, 0, w, lane);
    __syncthreads();   // drains vmcnt(0): group 0 resident

    for (int g = 0; g < NGRP; ++g) {
        if (g + 1 < NGRP)
            stage_grp(ehib, elob, enqb, lds + ((g + 1) & 1) * GBYTES, chunk, g + 1, w, lane);
        const char* bb = lds + (g & 1) * GBYTES;
#pragma unroll
        for (int tt = 0; tt < GRP; ++tt) {
            half8 bh = *(const half8*)(bb + tt * 1024 + lane * 16);
            half8 bl = *(const half8*)(bb + 8192 + tt * 1024 + lane * 16);
            f32x4 eq = *(const f32x4*)(bb + 16384 + tt * 256 + (lane & 15) * 16);
#pragma unroll
            for (int qq = 0; qq < 4; ++qq) {
                f32x4 acc = __builtin_amdgcn_mfma_f32_16x16x32_f16(a_hi[qq], bh, eq, 0, 0, 0);
                acc = __builtin_amdgcn_mfma_f32_16x16x32_f16(a_hi[qq], bl, acc, 0, 0, 0);
                acc = __builtin_amdgcn_mfma_f32_16x16x32_f16(a_lo[qq], bh, acc, 0, 0, 0);
#pragma unroll
                for (int r = 0; r < 4; ++r) {
                    if (acc[r] < best[qq][r]) { best[qq][r] = acc[r]; bt[qq][r] = g * GRP + tt; }
                }
            }
        }
        __syncthreads();   // all waves done with buf[g&1]; next stage drained
    }

    // 16-lane column reduce per query row, then one atomicMin per query
#pragma unroll
    for (int qq = 0; qq < 4; ++qq)
#pragma unroll
        for (int r = 0; r < 4; ++r) {
            float d = best[qq][r];
            int code = chunk * CODES_PER_CH + (bt[qq][r] << 4) + (lane & 15);
#pragma unroll
            for (int m = 1; m < 16; m <<= 1) {
                float od = __shfl_xor(d, m, 64);
                int oc = __shfl_xor(code, m, 64);
                if (od < d || (od == d && oc < code)) { d = od; code = oc; }
            }
            if ((lane & 15) == 0) {
                int row = ((lane >> 4) * 4) + r;
                int n = (wid * 4 + qq) * 16 + row;
                unsigned bits = __float_as_uint(d);
                unsigned s = ((int)bits >= 0) ? (bits | 0x80000000u) : ~bits;
                unsigned long long key = ((unsigned long long)s << 32) | (unsigned)code;
                atomicMin(&keys[n], key);
            }
        }
}

// ---- conv3x3 residual + fhat + loss partials + bincount (keys-direct gather) ----
__global__ __launch_bounds__(256) void k_conv(const unsigned long long* __restrict__ keys,
                                              const float* __restrict__ emb,
                                              const float* __restrict__ wp,
                                              const float* __restrict__ bias,
                                              const float* __restrict__ f,
                                              int* __restrict__ counts,
                                              float* __restrict__ out,
                                              float* __restrict__ lpart) {
    __shared__ float sZ[128 * 33];
    __shared__ float sW[9216];      // full [tap][cin][cout] weight block
    __shared__ float red[256];
    int blk = blockIdx.x;
    int b = blk >> 4;
    int r0 = (blk & 15) * 2;
    int tid = threadIdx.x;

    {   // stage weights: 2304 float4
        float4* dW = reinterpret_cast<float4*>(sW);
        const float4* sWp = reinterpret_cast<const float4*>(wp);
        for (int i = tid; i < 2304; i += 256) dW[i] = sWp[i];
    }
    {   // stage 4 rows (r0-1..r0+2): 128 px x 2 half-rows of channels
        int px = tid >> 1, half = tid & 1;
        int row = px >> 5, col = px & 31;
        int gy = r0 - 1 + row;
        float* d = &sZ[px * 33 + half * 16];
        if (gy >= 0 && gy < 32) {
            int id = (int)(keys[b * HW + gy * 32 + col] & 0xFFFFFFFFULL);
            const float4* s = reinterpret_cast<const float4*>(emb + id * C + half * 16);
#pragma unroll
            for (int k = 0; k < 4; ++k) {
                float4 v = s[k];
                d[4 * k] = v.x; d[4 * k + 1] = v.y; d[4 * k + 2] = v.z; d[4 * k + 3] = v.w;
            }
        } else {
#pragma unroll
            for (int k = 0; k < 16; ++k) d[k] = 0.f;
        }
    }
    __syncthreads();

    int tx = tid & 31, ty = (tid >> 5) & 1, cg = tid >> 6;
    int co0 = cg * 8;
    int gy = r0 + ty;
    if (cg == 0) {
        int id = (int)(keys[b * HW + gy * 32 + tx] & 0xFFFFFFFFULL);
        atomicAdd(&counts[id], 1);
    }
    float acc[8];
#pragma unroll
    for (int u = 0; u < 8; ++u) acc[u] = bias[co0 + u];
    for (int dy = -1; dy <= 1; ++dy) {
        for (int dx = -1; dx <= 1; ++dx) {
            int gx = tx + dx;
            if (gx < 0 || gx >= 32) continue;
            const float* zp = &sZ[((ty + 1 + dy) * 32 + gx) * 33];
            int tap = (dy + 1) * 3 + (dx + 1);
            const float* wtap = &sW[tap * C * C + co0];
#pragma unroll
            for (int cin = 0; cin < C; ++cin) {
                float z = zp[cin];
                const f32x4* w4 = reinterpret_cast<const f32x4*>(wtap + cin * C);
                f32x4 wa = w4[0], wb = w4[1];
#pragma unroll
                for (int u = 0; u < 4; ++u) acc[u] = fmaf(z, wa[u], acc[u]);
#pragma unroll
                for (int u = 0; u < 4; ++u) acc[4 + u] = fmaf(z, wb[u], acc[4 + u]);
            }
        }
    }
    float lsum = 0.f;
#pragma unroll
    for (int u = 0; u < 8; ++u) {
        int cc = co0 + u;
        float zqv = sZ[((ty + 1) * 32 + tx) * 33 + cc];
        float fh = 0.5f * (zqv + acc[u]);   // h*(1-r) + (conv+b)*r, r=0.5
        int off = (b * C + cc) * HW + gy * 32 + tx;
        out[off] = fh;
        float diff = fh - f[off];
        lsum += diff * diff;
    }
    red[tid] = lsum;
    __syncthreads();
    for (int s = 128; s > 0; s >>= 1) {
        if (tid < s) red[tid] += red[tid + s];
        __syncthreads();
    }
    if (tid == 0) lpart[blk] = red[0];
}

// ---- scalars ----
__global__ __launch_bounds__(256) void k_final(const float* __restrict__ lpart,
                                               const int* __restrict__ counts,
                                               float* __restrict__ out) {
    __shared__ float red[256];
    __shared__ int redi[256];
    int tid = threadIdx.x;
    int used = 0;
    for (int i = tid; i < VOCAB; i += 256) used += (counts[i] != 0) ? 1 : 0;
    red[tid] = lpart[tid];
    redi[tid] = used;
    __syncthreads();
    for (int s = 128; s > 0; s >>= 1) {
        if (tid < s) { red[tid] += red[tid + s]; redi[tid] += redi[tid + s]; }
        __syncthreads();
    }
    if (tid == 0) {
        out[N_Q * C]     = 1.25f * red[0] / (float)(N_Q * C);      // (1+BETA)*MSE
        out[N_Q * C + 1] = 100.f * (float)redi[0] / (float)VOCAB;  // counts>=1
    }
}

extern "C" void kernel_launch(void* const* d_in, const int* in_sizes, int n_in,
                              void* d_out, int out_size, void* d_ws, size_t ws_size,
                              hipStream_t stream) {
    const float* f     = (const float*)d_in[0];
    const float* emb   = (const float*)d_in[1];
    const float* convw = (const float*)d_in[2];
    const float* convb = (const float*)d_in[3];
    float* out = (float*)d_out;
    float* ws  = (float*)d_ws;

    // float-unit offsets (total 648,448 floats ~= 2.6 MB)
    float*  wp     = ws;                              // 9216
    float*  lpart  = ws + 9216;                       // 256
    int*    counts = (int*)(ws + 9472);               // 16384
    unsigned long long* keys = (unsigned long long*)(ws + 25856);  // 16384 u64
    float*  enq    = ws + 58624;                      // 65536 (quad ||e||^2/2)
    _Float16* Ehi  = (_Float16*)(ws + 124160);        // 524288 halves
    _Float16* Elo  = (_Float16*)(ws + 386304);        // 524288 halves

    k_prepE<<<67, 256, 0, stream>>>(emb, enq, Ehi, Elo, convw, wp, keys, counts);
    dim3 g2(64, VCH);
    k_argmin<<<g2, 256, 0, stream>>>(f, Ehi, Elo, enq, keys);
    k_conv<<<256, 256, 0, stream>>>(keys, emb, wp, convb, f, counts, out, lpart);
    k_final<<<1, 256, 0, stream>>>(lpart, counts, out);
}

// Round 11
// 88.628 us; speedup vs baseline: 5.4103x; 1.0374x over previous
//
#include <hip/hip_runtime.h>

#define VOCAB 16384
#define N_Q   16384   // B*h*w = 16*32*32
#define C     32
#define HW    1024    // h*w
#define VCH   16
#define CODES_PER_CH 1024
#define TILES_PER_CH 64
#define GRP    8          // tiles per staging group
#define NGRP   8          // groups per chunk
#define GBYTES 18432      // [8KB hi | 8KB lo | 2KB enq] contiguous blob

typedef _Float16 half8 __attribute__((ext_vector_type(8)));
typedef float f32x4  __attribute__((ext_vector_type(4)));

// ---- fused prep: E -> contiguous 18KB group blobs (f16 hi/lo frags + enq quads),
//      + conv wpack + keys/counts init ----
// frag layout (HW-verified r6-r10): within tile, lane=(ko<<4)|(j&15), elem 0..7
__global__ __launch_bounds__(256) void k_prepE(const float* __restrict__ emb,
                                               char* __restrict__ Eblob,
                                               const float* __restrict__ convw,
                                               float* __restrict__ wp,
                                               unsigned long long* __restrict__ keys,
                                               int* __restrict__ counts) {
    int bx = blockIdx.x;
    if (bx >= 64) {
        if (bx == 64) {          // conv-weight repack to [tap][cin][cout]
            for (int k = threadIdx.x; k < C * C * 9; k += 256) {
                int cout = k / (C * 9);
                int r = k % (C * 9);
                int cin = r / 9;
                int tap = r % 9;
                wp[(tap * C + cin) * C + cout] = convw[k];
            }
        } else if (bx == 65) {
            for (int k = threadIdx.x; k < VOCAB; k += 256) keys[k] = ~0ULL;
        } else {
            for (int k = threadIdx.x; k < VOCAB; k += 256) counts[k] = 0;
        }
        return;
    }
    int j = bx * 256 + threadIdx.x;   // code row
    const float4* e4 = reinterpret_cast<const float4*>(emb + j * C);
    float s = 0.f;
    float v[C];
#pragma unroll
    for (int k = 0; k < 8; ++k) {
        float4 t = e4[k];
        v[4 * k] = t.x; v[4 * k + 1] = t.y; v[4 * k + 2] = t.z; v[4 * k + 3] = t.w;
        s += t.x * t.x + t.y * t.y + t.z * t.z + t.w * t.w;
    }
    float en2 = 0.5f * s;
    int tg = j >> 4, G = tg >> 3, tt = tg & 7;
    char* gb = Eblob + (size_t)G * GBYTES;
    *reinterpret_cast<float4*>(gb + 16384 + tt * 256 + (j & 15) * 16)
        = make_float4(en2, en2, en2, en2);
#pragma unroll
    for (int ko = 0; ko < 4; ++ko) {
        half8 vh, vl;
#pragma unroll
        for (int e = 0; e < 8; ++e) {
            float x = v[ko * 8 + e];
            _Float16 h = (_Float16)x;
            vh[e] = h;
            vl[e] = (_Float16)(x - (float)h);
        }
        int lane = (ko << 4) | (j & 15);
        *reinterpret_cast<half8*>(gb + tt * 1024 + lane * 16) = vh;
        *reinterpret_cast<half8*>(gb + 8192 + tt * 1024 + lane * 16) = vl;
    }
}

// ---- staging: one 18KB contiguous blob -> LDS via global_load_lds(16B), branch-free ----
__device__ __forceinline__ void stage_grp(const char* gb, char* db, int w, int lane) {
#pragma unroll
    for (int k = 0; k < 5; ++k) {
        int widx = w + 4 * k;     // 18 wave-copies of 1KB over 4 waves
        if (widx < 18) {
            __builtin_amdgcn_global_load_lds(
                (const __attribute__((address_space(1))) void*)(gb + widx * 1024 + lane * 16),
                (__attribute__((address_space(3))) void*)(db + widx * 1024 + lane * 16),
                16, 0, 0);
        }
    }
}

// ---- MFMA argmin: packed running-min; d' = ||e||^2/2 - q.e ; f16 3-way split ----
// block = 4 waves x 64 queries; grid (64, 16 chunks)
__global__ __launch_bounds__(256, 3) void k_argmin(
    const float* __restrict__ f,
    const char* __restrict__ Eblob,
    unsigned long long* __restrict__ keys) {
    __shared__ __align__(16) char lds[2 * GBYTES];
    int tid = threadIdx.x;
    int lane = tid & 63;
    int w = tid >> 6;
    int wid = blockIdx.x * 4 + w;        // 0..255, 64 queries each
    int chunk = blockIdx.y;

    // Q prologue: load 64 queries from f (NCHW), negate, f16 hi/lo split
    half8 a_hi[4], a_lo[4];
    int c0 = (lane >> 4) * 8;
#pragma unroll
    for (int qq = 0; qq < 4; ++qq) {
        int n = (wid * 4 + qq) * 16 + (lane & 15);
        int b = n >> 10, rem = n & 1023;
        const float* fp = f + (b * C + c0) * HW + rem;
#pragma unroll
        for (int e = 0; e < 8; ++e) {
            float x = -fp[e * HW];            // negated
            _Float16 h = (_Float16)x;
            a_hi[qq][e] = h;
            a_lo[qq][e] = (_Float16)(x - (float)h);
        }
    }

    float best[4][4];
#pragma unroll
    for (int qq = 0; qq < 4; ++qq)
#pragma unroll
        for (int r = 0; r < 4; ++r) best[qq][r] = __uint_as_float(0x7F800000u);  // +inf

    const char* gb0 = Eblob + (size_t)(chunk * NGRP) * GBYTES;

    stage_grp(gb0, lds, w, lane);
    __syncthreads();   // group 0 resident

    const char* bbl = lds + lane * 16;            // hi/lo base (per-lane)
    const char* ebl = lds + 16384 + (lane & 15) * 16;  // enq base

    for (int g = 0; g < NGRP; ++g) {
        if (g + 1 < NGRP)
            stage_grp(gb0 + (size_t)(g + 1) * GBYTES, lds + ((g + 1) & 1) * GBYTES, w, lane);
        int boff = (g & 1) * GBYTES;
#pragma unroll
        for (int tt = 0; tt < GRP; ++tt) {
            half8 bh = *(const half8*)(bbl + boff + tt * 1024);
            half8 bl = *(const half8*)(bbl + boff + 8192 + tt * 1024);
            f32x4 eq = *(const f32x4*)(ebl + boff + tt * 256);
            unsigned t = (unsigned)(g * GRP + tt);
#pragma unroll
            for (int qq = 0; qq < 4; ++qq) {
                f32x4 acc = __builtin_amdgcn_mfma_f32_16x16x32_f16(a_hi[qq], bh, eq, 0, 0, 0);
                acc = __builtin_amdgcn_mfma_f32_16x16x32_f16(a_hi[qq], bl, acc, 0, 0, 0);
                acc = __builtin_amdgcn_mfma_f32_16x16x32_f16(a_lo[qq], bh, acc, 0, 0, 0);
#pragma unroll
                for (int r = 0; r < 4; ++r) {
                    float pk = __uint_as_float((__float_as_uint(acc[r]) & 0xFFFFFFC0u) | t);
                    best[qq][r] = fminf(best[qq][r], pk);
                }
            }
        }
        __syncthreads();   // all waves done with buf[g&1]; next stage drained
    }

    // 16-lane column reduce per query row, then one atomicMin per query
#pragma unroll
    for (int qq = 0; qq < 4; ++qq)
#pragma unroll
        for (int r = 0; r < 4; ++r) {
            float d = best[qq][r];
            int t = (int)(__float_as_uint(d) & 63u);
            int code = chunk * CODES_PER_CH + (t << 4) + (lane & 15);
#pragma unroll
            for (int m = 1; m < 16; m <<= 1) {
                float od = __shfl_xor(d, m, 64);
                int oc = __shfl_xor(code, m, 64);
                if (od < d || (od == d && oc < code)) { d = od; code = oc; }
            }
            if ((lane & 15) == 0) {
                int row = ((lane >> 4) * 4) + r;
                int n = (wid * 4 + qq) * 16 + row;
                unsigned bits = __float_as_uint(d);
                unsigned s = ((int)bits >= 0) ? (bits | 0x80000000u) : ~bits;
                unsigned long long key = ((unsigned long long)s << 32) | (unsigned)code;
                atomicMin(&keys[n], key);
            }
        }
}

// ---- conv3x3 residual + fhat + loss partials + bincount (keys-direct gather) ----
__global__ __launch_bounds__(256) void k_conv(const unsigned long long* __restrict__ keys,
                                              const float* __restrict__ emb,
                                              const float* __restrict__ wp,
                                              const float* __restrict__ bias,
                                              const float* __restrict__ f,
                                              int* __restrict__ counts,
                                              float* __restrict__ out,
                                              float* __restrict__ lpart) {
    __shared__ float sZ[128 * 33];
    __shared__ float sW[9216];      // full [tap][cin][cout] weight block
    __shared__ float red[256];
    int blk = blockIdx.x;
    int b = blk >> 4;
    int r0 = (blk & 15) * 2;
    int tid = threadIdx.x;

    {   // stage weights: 2304 float4
        float4* dW = reinterpret_cast<float4*>(sW);
        const float4* sWp = reinterpret_cast<const float4*>(wp);
        for (int i = tid; i < 2304; i += 256) dW[i] = sWp[i];
    }
    {   // stage 4 rows (r0-1..r0+2)
        int px = tid >> 1, half = tid & 1;
        int row = px >> 5, col = px & 31;
        int gy = r0 - 1 + row;
        float* d = &sZ[px * 33 + half * 16];
        if (gy >= 0 && gy < 32) {
            int id = (int)(keys[b * HW + gy * 32 + col] & 0xFFFFFFFFULL);
            const float4* s = reinterpret_cast<const float4*>(emb + id * C + half * 16);
#pragma unroll
            for (int k = 0; k < 4; ++k) {
                float4 v = s[k];
                d[4 * k] = v.x; d[4 * k + 1] = v.y; d[4 * k + 2] = v.z; d[4 * k + 3] = v.w;
            }
        } else {
#pragma unroll
            for (int k = 0; k < 16; ++k) d[k] = 0.f;
        }
    }
    __syncthreads();

    int tx = tid & 31, ty = (tid >> 5) & 1, cg = tid >> 6;
    int co0 = cg * 8;
    int gy = r0 + ty;
    if (cg == 0) {
        int id = (int)(keys[b * HW + gy * 32 + tx] & 0xFFFFFFFFULL);
        atomicAdd(&counts[id], 1);
    }
    float acc[8];
#pragma unroll
    for (int u = 0; u < 8; ++u) acc[u] = bias[co0 + u];
    for (int dy = -1; dy <= 1; ++dy) {
        for (int dx = -1; dx <= 1; ++dx) {
            int gx = tx + dx;
            if (gx < 0 || gx >= 32) continue;
            const float* zp = &sZ[((ty + 1 + dy) * 32 + gx) * 33];
            int tap = (dy + 1) * 3 + (dx + 1);
            const float* wtap = &sW[tap * C * C + co0];
#pragma unroll
            for (int cin = 0; cin < C; ++cin) {
                float z = zp[cin];
                const f32x4* w4 = reinterpret_cast<const f32x4*>(wtap + cin * C);
                f32x4 wa = w4[0], wb = w4[1];
#pragma unroll
                for (int u = 0; u < 4; ++u) acc[u] = fmaf(z, wa[u], acc[u]);
#pragma unroll
                for (int u = 0; u < 4; ++u) acc[4 + u] = fmaf(z, wb[u], acc[4 + u]);
            }
        }
    }
    float lsum = 0.f;
#pragma unroll
    for (int u = 0; u < 8; ++u) {
        int cc = co0 + u;
        float zqv = sZ[((ty + 1) * 32 + tx) * 33 + cc];
        float fh = 0.5f * (zqv + acc[u]);   // h*(1-r) + (conv+b)*r, r=0.5
        int off = (b * C + cc) * HW + gy * 32 + tx;
        out[off] = fh;
        float diff = fh - f[off];
        lsum += diff * diff;
    }
    red[tid] = lsum;
    __syncthreads();
    for (int s = 128; s > 0; s >>= 1) {
        if (tid < s) red[tid] += red[tid + s];
        __syncthreads();
    }
    if (tid == 0) lpart[blk] = red[0];
}

// ---- scalars ----
__global__ __launch_bounds__(256) void k_final(const float* __restrict__ lpart,
                                               const int* __restrict__ counts,
                                               float* __restrict__ out) {
    __shared__ float red[256];
    __shared__ int redi[256];
    int tid = threadIdx.x;
    int used = 0;
    for (int i = tid; i < VOCAB; i += 256) used += (counts[i] != 0) ? 1 : 0;
    red[tid] = lpart[tid];
    redi[tid] = used;
    __syncthreads();
    for (int s = 128; s > 0; s >>= 1) {
        if (tid < s) { red[tid] += red[tid + s]; redi[tid] += redi[tid + s]; }
        __syncthreads();
    }
    if (tid == 0) {
        out[N_Q * C]     = 1.25f * red[0] / (float)(N_Q * C);      // (1+BETA)*MSE
        out[N_Q * C + 1] = 100.f * (float)redi[0] / (float)VOCAB;  // counts>=1
    }
}

extern "C" void kernel_launch(void* const* d_in, const int* in_sizes, int n_in,
                              void* d_out, int out_size, void* d_ws, size_t ws_size,
                              hipStream_t stream) {
    const float* f     = (const float*)d_in[0];
    const float* emb   = (const float*)d_in[1];
    const float* convw = (const float*)d_in[2];
    const float* convb = (const float*)d_in[3];
    float* out = (float*)d_out;
    float* ws  = (float*)d_ws;

    // float-unit offsets (total ~2.6 MB)
    float*  wp     = ws;                              // 9216
    float*  lpart  = ws + 9216;                       // 256
    int*    counts = (int*)(ws + 9472);               // 16384
    unsigned long long* keys = (unsigned long long*)(ws + 25856);  // 16384 u64
    char*   Eblob  = (char*)(ws + 58624);             // 128 groups x 18KB = 2.304 MB

    k_prepE<<<67, 256, 0, stream>>>(emb, Eblob, convw, wp, keys, counts);
    dim3 g2(64, VCH);
    k_argmin<<<g2, 256, 0, stream>>>(f, Eblob, keys);
    k_conv<<<256, 256, 0, stream>>>(keys, emb, wp, convb, f, counts, out, lpart);
    k_final<<<1, 256, 0, stream>>>(lpart, counts, out);
}